// Round 13
// baseline (220.060 us; speedup 1.0000x reference)
//
#include <hip/hip_runtime.h>

typedef unsigned int u32;
typedef unsigned short u16;
typedef unsigned long long ull;

constexpr int kB = 16, kT = 16, kN = 184, kD = 128, kH = 8, kHD = 16;
constexpr int kBT = kB * kT;            // 256
constexpr int kRows = kBT * kN;         // 47104
constexpr int kTile = kN * kHD;         // 2944 elements per (hb,t) tile
// softmax scale folded into q at projection: 0.25 * log2(e)
#define KQSCALE 0.36067376022224085f

typedef __attribute__((ext_vector_type(8))) short bf16x8;
typedef __attribute__((ext_vector_type(4))) float f32x4;

union FragU {
  bf16x8 f;
  ull u[2];
  uint4 q;
  u16 h[8];
};

#define MFMA(a, b, c) __builtin_amdgcn_mfma_f32_16x16x32_bf16((a), (b), (c), 0, 0, 0)

__device__ __forceinline__ float bf2f(u16 v) {
  return __uint_as_float(((u32)v) << 16);
}
__device__ __forceinline__ u16 f2bf(float f) {
  u32 x = __float_as_uint(f);
  x += 0x7fffu + ((x >> 16) & 1u);   // RNE
  return (u16)(x >> 16);
}
// pack two fp32 -> two bf16 (RNE) in one u32: lo in [15:0], hi in [31:16]
__device__ __forceinline__ u32 pack_bf2(float lo, float hi) {
  u32 a = __float_as_uint(lo); a += 0x7fffu + ((a >> 16) & 1u);
  u32 b = __float_as_uint(hi); b += 0x7fffu + ((b >> 16) & 1u);
  return __builtin_amdgcn_perm(b, a, 0x07060302);
}
// pack two fp32 -> two bf16 (truncate) in one u32 — single v_perm
__device__ __forceinline__ u32 pack_trunc(float lo, float hi) {
  return __builtin_amdgcn_perm(__float_as_uint(hi), __float_as_uint(lo), 0x07060302);
}
__device__ __forceinline__ u16 trunc_bf(float f) {
  return (u16)(__float_as_uint(f) >> 16);
}

// ---------------------------------------------------------------------------
// Kernel A (merged): blockIdx.y 0..2 = q/k/v projection GEMM, r20 geometry:
// each block computes 128 rows x 64 OUTPUT COLS (col-half ch = bx&1, tile =
// bx>>1 — pairs adjacent so the duplicated A read is L3-concurrent).
// W-tile shrinks to [64][136] -> LDS pool 52,224 B -> 3 blocks/CU (was 2),
// same 4-barrier structure, half the MFMAs per block, 2x blocks for tail.
// blockIdx.y == 3, blockIdx.x < 12 = adp softmax fragments (concurrent).
// ---------------------------------------------------------------------------
__global__ __launch_bounds__(256) void proj_kernel(
    const float* __restrict__ qin, const float* __restrict__ kin, const float* __restrict__ vin,
    const float* __restrict__ Wq, const float* __restrict__ Wk, const float* __restrict__ Wv,
    const float* __restrict__ bq, const float* __restrict__ bk, const float* __restrict__ bv,
    u16* __restrict__ qo, u16* __restrict__ ko, u16* __restrict__ vo,
    const float* __restrict__ ne1, const float* __restrict__ ne2,
    u16* __restrict__ arr3, u16* __restrict__ arr4) {
  __shared__ float smem_f[13056];          // 52,224 B pool
  const int tid = threadIdx.x;

  if (blockIdx.y == 3) {
    // ================= adp role (12 blocks) =================
    if (blockIdx.x >= 12) return;
    float* const s1  = smem_f;             // [kN*10]
    float* const s2  = smem_f + 1840;      // [10*kN]
    float* const l1r = smem_f + 3680;      // [kN]
    float* const l2c = smem_f + 3864;      // [kN]

    for (int i = tid; i < kN * 10; i += 256) { s1[i] = ne1[i]; s2[i] = ne2[i]; }
    __syncthreads();

    if (tid < kN) {
      const int r = tid;
      float reg[10];
#pragma unroll
      for (int e = 0; e < 10; ++e) reg[e] = s1[r * 10 + e];
      float sum = 0.f;
      for (int c = 0; c < kN; ++c) {
        float d = 0.f;
#pragma unroll
        for (int e = 0; e < 10; ++e) d += reg[e] * s2[e * kN + c];
        sum += __expf(d);
      }
      l1r[r] = sum;

      const int c = tid;
      float regc[10];
#pragma unroll
      for (int e = 0; e < 10; ++e) regc[e] = s2[e * kN + c];
      sum = 0.f;
      for (int r2 = 0; r2 < kN; ++r2) {
        float d = 0.f;
#pragma unroll
        for (int e = 0; e < 10; ++e) d += s1[r2 * 10 + e] * regc[e];
        sum += __expf(d);
      }
      l2c[c] = sum;
    }
    __syncthreads();

    for (int ee = blockIdx.x * 256 + tid; ee < 12 * 6 * 64; ee += 12 * 256) {
      const int i = ee / 384;
      const int rem = ee - i * 384;
      const int p = rem >> 6;
      const int lane = rem & 63;
      const int row = i * 16 + (lane & 15);
      const int cb = p * 32 + (lane >> 4) * 8;
      FragU fo3, fo4;
      const bool rok = row < kN;
      float inv1 = 0.f, inv2 = 0.f;
      float rreg[10], creg[10];
      if (rok) {
        inv1 = 1.f / l1r[row];
        inv2 = 1.f / l2c[row];
#pragma unroll
        for (int e = 0; e < 10; ++e) {
          rreg[e] = s1[row * 10 + e];
          creg[e] = s2[e * kN + row];
        }
      }
#pragma unroll
      for (int j = 0; j < 8; ++j) {
        const int col = cb + j;
        float v3 = 0.f, v4 = 0.f;
        if (rok && col < kN) {
          float d3 = 0.f, d4 = 0.f;
#pragma unroll
          for (int e = 0; e < 10; ++e) {
            d3 += rreg[e] * s2[e * kN + col];
            d4 += s1[col * 10 + e] * creg[e];
          }
          v3 = __expf(d3) * inv1;
          v4 = __expf(d4) * inv2;
        }
        fo3.h[j] = f2bf(v3);
        fo4.h[j] = f2bf(v4);
      }
      *(uint4*)(arr3 + (size_t)ee * 8) = fo3.q;
      *(uint4*)(arr4 + (size_t)ee * 8) = fo4.q;
    }
    return;
  }

  // ================= projection role (128 rows x 64 cols) =================
  u16* const s_w = (u16*)smem_f;            // [64][136]  (17,408 B)
  u16* const s_a = (u16*)smem_f + 64 * 136; // [128][136] (34,816 B)

  const float* in; const float* Wf; const float* bias; u16* out; float scale;
  if (blockIdx.y == 0)      { in = qin; Wf = Wq; bias = bq; out = qo; scale = KQSCALE; }
  else if (blockIdx.y == 1) { in = kin; Wf = Wk; bias = bk; out = ko; scale = 1.f; }
  else                      { in = vin; Wf = Wv; bias = bv; out = vo; scale = 1.f; }

  const int tile = blockIdx.x >> 1, ch = blockIdx.x & 1;
  const int r0 = tile * 128;
  {
    // stage W col-half: W rows ch*64..ch*64+63 (output cols), all 128 K.
    for (int i = tid; i < 1024; i += 256) {
      const int row = i >> 4, c8 = (i & 15) * 8;
      const float* wp = Wf + (size_t)(ch * 64 + row) * 128 + c8;
      const float4 w0 = *(const float4*)wp;
      const float4 w1 = *(const float4*)(wp + 4);
      *(uint4*)(s_w + row * 136 + c8) =
          make_uint4(pack_bf2(w0.x, w0.y), pack_bf2(w0.z, w0.w),
                     pack_bf2(w1.x, w1.y), pack_bf2(w1.z, w1.w));
    }
    // stage A-tile (coalesced float4, bf16 RNE)
    const float* abase = in + (size_t)r0 * 128;
#pragma unroll
    for (int i = 0; i < 16; ++i) {
      const int idx = i * 1024 + tid * 4;
      const float4 v = *(const float4*)(abase + idx);
      const int row = idx >> 7, col = idx & 127;
      *(u32*)(s_a + row * 136 + col)     = pack_bf2(v.x, v.y);
      *(u32*)(s_a + row * 136 + col + 2) = pack_bf2(v.z, v.w);
    }
  }
  __syncthreads();

  const int w = tid >> 6, lane = tid & 63, quad = lane >> 4, m = lane & 15;

  f32x4 acc0[4], acc1[4];
  const f32x4 z4 = {0.f, 0.f, 0.f, 0.f};
#pragma unroll
  for (int ct = 0; ct < 4; ++ct) { acc0[ct] = z4; acc1[ct] = z4; }

  const u16* ap0 = s_a + (w * 16 + m) * 136 + quad * 8;
  const u16* ap1 = ap0 + 64 * 136;

#pragma unroll
  for (int kp = 0; kp < 4; ++kp) {
    FragU a0; a0.q = *(const uint4*)(ap0 + kp * 32);
    FragU a1; a1.q = *(const uint4*)(ap1 + kp * 32);
#pragma unroll
    for (int ct = 0; ct < 4; ++ct) {
      FragU bfr; bfr.q = *(const uint4*)(s_w + (ct * 16 + m) * 136 + kp * 32 + quad * 8);
      acc0[ct] = MFMA(a0.f, bfr.f, acc0[ct]);
      acc1[ct] = MFMA(a1.f, bfr.f, acc1[ct]);
    }
  }

  float bc[4];
#pragma unroll
  for (int ct = 0; ct < 4; ++ct) bc[ct] = bias[ch * 64 + ct * 16 + m];

  // ---- epilogue: bounce through s_a (dead after MFMA loop), then 4 fully-
  // coalesced uint4 stores per thread (one per ct-plane).
  __syncthreads();   // all waves done reading s_a as A-fragments
#pragma unroll
  for (int half = 0; half < 2; ++half) {
    const f32x4* acc = half ? acc1 : acc0;
    const int rloc = (w + half * 4) * 16 + quad * 4;   // 0..127
#pragma unroll
    for (int rr = 0; rr < 4; ++rr) {
#pragma unroll
      for (int ct = 0; ct < 4; ++ct)
        s_a[(rloc + rr) * 136 + ct * 16 + m] = f2bf((acc[ct][rr] + bc[ct]) * scale);
    }
  }
  __syncthreads();

  const int prow = tid >> 1, phr = (tid & 1) * 8;   // 128 rows x 2 halves
#pragma unroll
  for (int ct = 0; ct < 4; ++ct) {
    const int plane = ch * 4 + ct;
    FragU v; v.q = *(const uint4*)(s_a + prow * 136 + ct * 16 + phr);
    *(uint4*)(out + (size_t)plane * kBT * kN * 16 + (size_t)(r0 + prow) * 16 + phr) = v.q;
  }
}

// ---------------------------------------------------------------------------
// Kernel 3: MFMA dual-softmax attention + adp mixing + fused Wm.
// r11 body + r19 vectorized V staging (verified 53.3 us, absmax 2e-3).
// ---------------------------------------------------------------------------
__global__ __launch_bounds__(256, 2) void attn_kernel(
    const u16* qg, const u16* __restrict__ kg, const u16* __restrict__ vg,
    const u16* __restrict__ arr3, const u16* __restrict__ arr4,
    const float* __restrict__ Wm, const float* __restrict__ bm,
    u16* mg) {
  __shared__ u16 pool[39424];              // 78848 B total
  u16* const s_E   = pool;                 // [192][72]  (13824 elems)
  u16* const s_ET0 = pool + 13824;         // [64][200]  (12800 elems)
  u16* const s_ET1 = pool + 26624;         // [64][200]  (12800 elems)
  u16* const s_vT  = s_ET1;                // alias: [16][200] (3200 elems)
  u16* const s_cat = s_ET1;                // alias: 4*1152 = 4608 elems

  const int tid = threadIdx.x;
  const size_t base = (size_t)blockIdx.x * kTile;
  const int w = tid >> 6, lane = tid & 63;
  const int quad = lane >> 4, m = lane & 15;

  // ---- stage V transposed into s_vT (vectorized: 384 uint4 reads)
  for (int i = tid; i < 384; i += 256) {
    const int t = i >> 1, c8 = (i & 1) * 8;
    FragU f;
    if (t < kN) f.q = *(const uint4*)(vg + base + t * 16 + c8);
    else { f.u[0] = 0; f.u[1] = 0; }
#pragma unroll
    for (int j = 0; j < 8; ++j) s_vT[(c8 + j) * 200 + t] = f.h[j];
  }

  // ---- K A-fragments (rows = k tokens) for ALL 12 k-tiles, from global.
  bf16x8 kfr[12];
#pragma unroll
  for (int t12 = 0; t12 < 12; ++t12) {
    FragU fk; fk.u[0] = 0; fk.u[1] = 0;
    const int tok = t12 * 16 + m;
    if (quad < 2 && tok < kN)
      fk.q = *(const uint4*)(kg + base + tok * 16 + quad * 8);
    kfr[t12] = fk.f;
  }
  // ---- Q B-fragments for this wave's own 3 q-tiles {w, w+4, w+8}.
  bf16x8 qB[3];
#pragma unroll
  for (int ti = 0; ti < 3; ++ti) {
    FragU fq; fq.u[0] = 0; fq.u[1] = 0;
    const int tok = (w + ti * 4) * 16 + m;
    if (quad < 2 && tok < kN)
      fq.q = *(const uint4*)(qg + base + tok * 16 + quad * 8);
    qB[ti] = fq.f;
  }

  // ---- Wm A-fragments with interleaved cat-dim mapping (unchanged).
  bf16x8 wmb[2];
#pragma unroll
  for (int kt = 0; kt < 2; ++kt) {
    FragU f;
#pragma unroll
    for (int j = 0; j < 8; ++j) {
      const int kdl = quad * 8 + j;
      const int orig = (kt * 2 + (kdl & 1)) * 16 + (kdl >> 1);
      f.h[j] = f2bf(Wm[m * 64 + orig]);
    }
    wmb[kt] = f.f;
  }
  const float4 bm4 = *(const float4*)(bm + quad * 4);

  // bar_a: s_vT ready AND all waves' qg reads drained (mg aliases qg; mg
  // writes happen only after bar3).
  __syncthreads();

  bf16x8 vb[6];   // V B-frags: B[token][ch]
#pragma unroll
  for (int p = 0; p < 6; ++p) {
    FragU f;
    f.q = *(const uint4*)(s_vT + m * 200 + p * 32 + quad * 8);
    vb[p] = f.f;
  }
  FragU onesU; onesU.u[0] = 0x3F803F803F803F80ULL; onesU.u[1] = onesU.u[0];
  const bf16x8 ones = onesU.f;
  const f32x4 zero4 = {0.f, 0.f, 0.f, 0.f};

  f32x4 o1[3], l1[3], o3[3], o4[3], o2[3], l2[3];
#pragma unroll
  for (int ti = 0; ti < 3; ++ti) {
    o1[ti] = zero4; l1[ti] = zero4; o3[ti] = zero4;
    o4[ti] = zero4; o2[ti] = zero4; l2[ti] = zero4;
  }

  // S_PHASE(CC, ETB): wave computes its 3 q-tiles x 4 k-tiles of E = exp2(S),
  // stores as b64 into s_E rows (own rows, wave-local) + b16 scatter into ETB.
#define S_PHASE(CC, ETB)                                                      \
  do {                                                                        \
    _Pragma("unroll") for (int ti = 0; ti < 3; ++ti) {                        \
      const int qt = w + ti * 4;                                              \
      const int qrow = qt * 16 + m;                                           \
      _Pragma("unroll") for (int ktl = 0; ktl < 4; ++ktl) {                   \
        f32x4 sv = MFMA(kfr[(CC) * 4 + ktl], qB[ti], zero4);                  \
        const float e0 = exp2f(sv[0]), e1 = exp2f(sv[1]);                     \
        const float e2 = exp2f(sv[2]), e3 = exp2f(sv[3]);                     \
        uint2 ev;                                                             \
        ev.x = pack_trunc(e0, e1);                                            \
        ev.y = pack_trunc(e2, e3);                                            \
        *(uint2*)(s_E + qrow * 72 + ktl * 16 + quad * 4) = ev;                \
        u16* etp = (ETB) + (ktl * 16 + quad * 4) * 200 + qrow;                \
        etp[0]   = trunc_bf(e0);                                              \
        etp[200] = trunc_bf(e1);                                              \
        etp[400] = trunc_bf(e2);                                              \
        etp[600] = trunc_bf(e3);                                              \
      }                                                                       \
    }                                                                         \
  } while (0)

#define LOAD_ARR(CC)                                                          \
  _Pragma("unroll") for (int ti = 0; ti < 3; ++ti) {                          \
    const int qt = w + ti * 4;                                                \
    _Pragma("unroll") for (int pl = 0; pl < 2; ++pl) {                        \
      const int pg = (CC) * 2 + pl;                                           \
      a3f[ti * 2 + pl].q = *(const uint4*)(arr3 + (size_t)((qt * 6 + pg) * 64 + lane) * 8); \
      a4f[ti * 2 + pl].q = *(const uint4*)(arr4 + (size_t)((qt * 6 + pg) * 64 + lane) * 8); \
    }                                                                         \
  }

  // ROW_PHASE(CC): reads own s_E rows (wave-local; no barrier dependency).
#define ROW_PHASE(CC)                                                         \
  _Pragma("unroll") for (int ti = 0; ti < 3; ++ti) {                          \
    const int qt = w + ti * 4;                                                \
    const u16* erp = s_E + (qt * 16 + m) * 72 + quad * 8;                     \
    _Pragma("unroll") for (int pl = 0; pl < 2; ++pl) {                        \
      const int pg = (CC) * 2 + pl;                                           \
      FragU pa; pa.q = *(const uint4*)(erp + pl * 32);                        \
      o1[ti] = MFMA(pa.f, vb[pg], o1[ti]);                                    \
      l1[ti] = MFMA(pa.f, ones, l1[ti]);                                      \
      o3[ti] = MFMA(a3f[ti * 2 + pl].f, vb[pg], o3[ti]);                      \
      o4[ti] = MFMA(a4f[ti * 2 + pl].f, vb[pg], o4[ti]);                      \
    }                                                                         \
  }

  // COL_PHASE(CC, ETB): reads E^T rows (cross-wave; requires barrier).
#define COL_PHASE(CC, ETB)                                                    \
  {                                                                           \
    const u16* etr = (ETB) + (w * 16 + m) * 200 + quad * 8;                   \
    _Pragma("unroll") for (int pg = 0; pg < 6; ++pg) {                        \
      FragU pT; pT.q = *(const uint4*)(etr + pg * 32);                        \
      o2[CC] = MFMA(pT.f, vb[pg], o2[CC]);                                    \
      l2[CC] = MFMA(pT.f, ones, l2[CC]);                                      \
    }                                                                         \
  }

  // ---- I0: produce chunk 0
  S_PHASE(0, s_ET0);
  __syncthreads();   // bar1: ET0 sealed; vb reads sealed before S1 hits ET1
  // ---- I1: consume chunk 0, produce chunk 1 (ROW0 reads s_E BEFORE S1
  //          overwrites it — WAR order)
  {
    FragU a3f[6], a4f[6];
    LOAD_ARR(0);
    COL_PHASE(0, s_ET0);
    ROW_PHASE(0);
    S_PHASE(1, s_ET1);
  }
  __syncthreads();   // bar2: ET1 sealed; COL0 done with ET0
  // ---- I2
  {
    FragU a3f[6], a4f[6];
    LOAD_ARR(1);
    COL_PHASE(1, s_ET1);
    ROW_PHASE(1);
    S_PHASE(2, s_ET0);
  }
  __syncthreads();   // bar3: ET0 sealed; COL1 done with ET1 (cat may reuse)
  // ---- I3
  {
    FragU a3f[6], a4f[6];
    LOAD_ARR(2);
    COL_PHASE(2, s_ET0);
    ROW_PHASE(2);
  }

#undef S_PHASE
#undef LOAD_ARR
#undef ROW_PHASE
#undef COL_PHASE

  // ================= fused Wm epilogue (per own tile) =================
  u16* cw = s_cat + w * 1152;
#pragma unroll
  for (int ti = 0; ti < 3; ++ti) {
    const int tt = w + ti * 4;
#pragma unroll
    for (int r = 0; r < 4; ++r) {
      const int token = quad * 4 + r;
      const float n1 = o1[ti][r] * __builtin_amdgcn_rcpf(l1[ti][r] - 8.0f);
      const float n2 = o2[ti][r] * __builtin_amdgcn_rcpf(l2[ti][r] - 8.0f);
      *(u32*)(cw + token * 72 + 2 * m)      = pack_bf2(n1, n2);       // dims 2m,2m+1
      *(u32*)(cw + token * 72 + 32 + 2 * m) = pack_bf2(o3[ti][r], o4[ti][r]);
    }
    f32x4 macc = {bm4.x, bm4.y, bm4.z, bm4.w};
#pragma unroll
    for (int kt = 0; kt < 2; ++kt) {
      FragU ca; ca.q = *(const uint4*)(cw + m * 72 + kt * 32 + quad * 8);
      macc = MFMA(wmb[kt], ca.f, macc);   // filt^T = Wm @ cat^T
    }
    if (tt * 16 + m < kN) {
      *(uint2*)(mg + base + (tt * 16 + m) * 16 + quad * 4) =
          make_uint2(pack_bf2(macc[0], macc[1]), pack_bf2(macc[2], macc[3]));
    }
  }
}

// ---------------------------------------------------------------------------
// Kernel 4: MFMA head-merge + Wo GEMM, fp32 out + bo (Wo staged from fp32
// with inline RNE conversion — unchanged).
// ---------------------------------------------------------------------------
__global__ __launch_bounds__(256) void out_kernel(
    const u16* __restrict__ mg, const float* __restrict__ Wo,
    const float* __restrict__ bo, float* __restrict__ outg) {
  __shared__ u16 s_w[128 * 136];
  const int tid = threadIdx.x;
  {
    for (int i = tid; i < 2048; i += 256) {
      const int row = i >> 4, c8 = (i & 15) * 8;
      const float4 w0 = *(const float4*)(Wo + row * 128 + c8);
      const float4 w1 = *(const float4*)(Wo + row * 128 + c8 + 4);
      *(uint4*)(s_w + row * 136 + c8) =
          make_uint4(pack_bf2(w0.x, w0.y), pack_bf2(w0.z, w0.w),
                     pack_bf2(w1.x, w1.y), pack_bf2(w1.z, w1.w));
    }
  }
  __syncthreads();

  const int w = tid >> 6, lane = tid & 63, quad = lane >> 4, m = lane & 15;
  const int r0 = blockIdx.x * 128;

  f32x4 acc0[8], acc1[8];
  const f32x4 z4 = {0.f, 0.f, 0.f, 0.f};
#pragma unroll
  for (int ct = 0; ct < 8; ++ct) { acc0[ct] = z4; acc1[ct] = z4; }

  const int hh = quad >> 1, hd8 = (quad & 1) * 8;
  const int ra = r0 + w * 16 + m;
  const int bt0 = ra / kN, n0 = ra - bt0 * kN;
  const int rb = ra + 64;
  const int bt1 = rb / kN, n1 = rb - bt1 * kN;
  const u16* mp0 = mg + ((size_t)(hh * kBT + bt0) * kN + n0) * 16 + hd8;
  const u16* mp1 = mg + ((size_t)(hh * kBT + bt1) * kN + n1) * 16 + hd8;
  const size_t hstep = (size_t)2 * kBT * kN * 16;

#pragma unroll
  for (int kp = 0; kp < 4; ++kp) {
    FragU a0; a0.q = *(const uint4*)(mp0 + kp * hstep);
    FragU a1; a1.q = *(const uint4*)(mp1 + kp * hstep);
#pragma unroll
    for (int ct = 0; ct < 8; ++ct) {
      FragU bfr; bfr.q = *(const uint4*)(s_w + (ct * 16 + m) * 136 + kp * 32 + quad * 8);
      acc0[ct] = MFMA(a0.f, bfr.f, acc0[ct]);
      acc1[ct] = MFMA(a1.f, bfr.f, acc1[ct]);
    }
  }

  float bc[8];
#pragma unroll
  for (int ct = 0; ct < 8; ++ct) bc[ct] = bo[ct * 16 + m];

#pragma unroll
  for (int half = 0; half < 2; ++half) {
    const f32x4* acc = half ? acc1 : acc0;
    const int rbase = r0 + (w + half * 4) * 16 + quad * 4;
#pragma unroll
    for (int rr = 0; rr < 4; ++rr) {
      float* op = outg + (size_t)(rbase + rr) * 128 + m;
#pragma unroll
      for (int ct = 0; ct < 8; ++ct)
        op[ct * 16] = acc[ct][rr] + bc[ct];
    }
  }
}

// ---------------------------------------------------------------------------
extern "C" void kernel_launch(void* const* d_in, const int* in_sizes, int n_in,
                              void* d_out, int out_size, void* d_ws, size_t ws_size,
                              hipStream_t stream) {
  const float* query = (const float*)d_in[0];
  const float* key   = (const float*)d_in[1];
  const float* value = (const float*)d_in[2];
  const float* Wq = (const float*)d_in[3];
  const float* bq = (const float*)d_in[4];
  const float* Wk = (const float*)d_in[5];
  const float* bk = (const float*)d_in[6];
  const float* Wv = (const float*)d_in[7];
  const float* bv = (const float*)d_in[8];
  const float* Wm = (const float*)d_in[9];
  const float* bm = (const float*)d_in[10];
  const float* Wo = (const float*)d_in[11];
  const float* bo = (const float*)d_in[12];
  const float* ne1 = (const float*)d_in[13];
  const float* ne2 = (const float*)d_in[14];

  const size_t tensor_bytes = (size_t)kH * kB * kT * kN * kHD * 2;  // 12,058,624
  const size_t frag_bytes = (size_t)12 * 6 * 64 * 8 * 2;            // 73,728
  char* ws = (char*)d_ws;
  u16* qs   = (u16*)(ws);                        // reused as m after attn
  u16* ks   = (u16*)(ws + tensor_bytes);
  u16* vs   = (u16*)(ws + 2 * tensor_bytes);
  u16* arr3 = (u16*)(ws + 3 * tensor_bytes);
  u16* arr4 = (u16*)(ws + 3 * tensor_bytes + frag_bytes);

  proj_kernel<<<dim3(kRows / 64, 4), 256, 0, stream>>>(
      query, key, value, Wq, Wk, Wv, bq, bk, bv, qs, ks, vs,
      ne1, ne2, arr3, arr4);
  attn_kernel<<<kH * kB * kT, 256, 0, stream>>>(qs, ks, vs, arr3, arr4, Wm, bm, qs);
  out_kernel<<<kRows / 128, 256, 0, stream>>>(qs, Wo, bo, (float*)d_out);
}